// Round 8
// baseline (244.205 us; speedup 1.0000x reference)
//
#include <hip/hip_runtime.h>
#include <hip/hip_bf16.h>
#include <stdint.h>

typedef __bf16 bf16x8 __attribute__((ext_vector_type(8)));
typedef float floatx4 __attribute__((ext_vector_type(4)));

#define B_ 2
#define L_ 4096
#define C_ 1024
#define H_ 16
#define D_ 64
constexpr size_t TEN = (size_t)B_ * H_ * L_ * D_;  // 8388608 elems per q/k/v tensor
#define LOG2E 1.4426950408889634f

__device__ __forceinline__ float bf2f(unsigned short u) {
  union { unsigned int i; float f; } x; x.i = ((unsigned int)u) << 16; return x.f;
}
// base-2 exp, maps to v_exp_f32 (AMDGCN's exp IS base-2)
__device__ __forceinline__ float exp2fast(float x) {
  return __builtin_amdgcn_exp2f(x);
}

// direct global->LDS async copy, 16B per lane (global_load_lds_dwordx4)
__device__ __forceinline__ void async_copy16(const unsigned short* g, unsigned short* l) {
  __builtin_amdgcn_global_load_lds(
      (const __attribute__((address_space(1))) unsigned int*)g,
      (__attribute__((address_space(3))) unsigned int*)l,
      16, 0, 0);
}

// ---------------- transpose f32 in -> bf16 out, dims divisible by 64 ----------------
__global__ __launch_bounds__(256) void transpose_f32_bf16(
    const float* __restrict__ in, unsigned short* __restrict__ out,
    int R, int Ccols) {
  __shared__ float tile[64][65];
  const int bx = blockIdx.x * 64;  // col base in input
  const int by = blockIdx.y * 64;  // row base in input
  const int t = threadIdx.x;
  for (int i = t; i < 1024; i += 256) {
    int r = i >> 4, c4 = (i & 15) << 2;
    float4 v = *(const float4*)&in[(size_t)(by + r) * Ccols + bx + c4];
    tile[r][c4] = v.x; tile[r][c4 + 1] = v.y; tile[r][c4 + 2] = v.z; tile[r][c4 + 3] = v.w;
  }
  __syncthreads();
  for (int i = t; i < 512; i += 256) {
    int r = i >> 3, c8 = (i & 7) << 3;  // r = output row (input col)
    union { uint4 u; __bf16 h[8]; } st;
    #pragma unroll
    for (int j = 0; j < 8; ++j) st.h[j] = (__bf16)tile[c8 + j][r];
    *(uint4*)&out[(size_t)(bx + r) * R + by + c8] = st.u;
  }
}

// ---------------- GEMM: A (MxK) * Bt^T (Bt is NxK, bf16), MFMA ----------------
// R5 core geometry: 128x128 tile, BK=64, 4 waves, XCD swizzle.
// B operand: global_load_lds width=16 + rule-#21 both-sides XOR (0 conflicts, R5).
// A operand, AF32=true: A is f32; reg-stage 2x float4 -> native cvt -> ds_write_b128
//   into pad-72 LDS (writes 32B/bank uniform; reads 2-way aliased = free). This
//   fuses the former cvt_f32_bf16 kernel into the GEMM (removes 50 MB HBM traffic).
// A operand, AF32=false: bf16, same gload_lds+XOR path as B (R5 exact).
// MODE 0: scatter into q/k/v (B,H,L,D) bf16 with bias; cols<1024 scaled by qscale
// MODE 1: plain C = A*B + bias -> out_f (MxN f32)
template <int MODE, bool AF32>
__global__ __launch_bounds__(256) void gemm_bt_kernel(
    const void* __restrict__ Av, const unsigned short* __restrict__ Bt,
    const float* __restrict__ bias, unsigned short* __restrict__ out_bf,
    float* __restrict__ out_f, int M, int N, int K, float qscale) {
  constexpr int BK = 64;
  constexpr int LDA = 72;  // pad for the AF32 ds_write path
  __shared__ unsigned short a_sh[128 * LDA];
  __shared__ unsigned short b_sh[128 * BK];

  const int t = threadIdx.x;
  // bijective XCD swizzle of flat block id (nwg % 8 == 0: 1536 / 512)
  const int nwgx = gridDim.x;
  const int nwg = nwgx * gridDim.y;
  const int flat = blockIdx.y * nwgx + blockIdx.x;
  const int cpx = nwg >> 3;
  const int swz = (flat & 7) * cpx + (flat >> 3);
  const int n0 = (swz % nwgx) * 128;
  const int m0 = (swz / nwgx) * 128;

  const int wave = t >> 6, lane = t & 63;
  const int wr = wave >> 1, wc = wave & 1;
  const int lm = lane & 15, quad = lane >> 4;

  const int srow = t >> 3;        // 0..31
  const int scol = (t & 7) * 8;   // 16B-aligned col offset

  floatx4 acc[4][4];
  #pragma unroll
  for (int i = 0; i < 4; ++i)
    #pragma unroll
    for (int j = 0; j < 4; ++j) acc[i][j] = (floatx4)0.0f;

  const float* Af = (const float*)Av;
  const unsigned short* Ab = (const unsigned short*)Av;

  for (int kt = 0; kt < K; kt += BK) {
    // B first: DMA in flight while A does VALU cvt work
    #pragma unroll
    for (int p = 0; p < 4; ++p) {
      int r = srow + p * 32;
      int c = scol ^ ((r & 7) << 3);   // inverse swizzle on source col
      async_copy16(&Bt[(size_t)(n0 + r) * K + kt + c], &b_sh[r * BK + scol]);
    }
    if (AF32) {
      #pragma unroll
      for (int p = 0; p < 4; ++p) {
        int r = srow + p * 32;
        const float* src = &Af[(size_t)(m0 + r) * K + kt + scol];
        float4 v0 = *(const float4*)src;
        float4 v1 = *(const float4*)(src + 4);
        union { uint4 u; __bf16 h[8]; } st;
        st.h[0] = (__bf16)v0.x; st.h[1] = (__bf16)v0.y;
        st.h[2] = (__bf16)v0.z; st.h[3] = (__bf16)v0.w;
        st.h[4] = (__bf16)v1.x; st.h[5] = (__bf16)v1.y;
        st.h[6] = (__bf16)v1.z; st.h[7] = (__bf16)v1.w;
        *(uint4*)&a_sh[r * LDA + scol] = st.u;
      }
    } else {
      #pragma unroll
      for (int p = 0; p < 4; ++p) {
        int r = srow + p * 32;
        int c = scol ^ ((r & 7) << 3);
        async_copy16(&Ab[(size_t)(m0 + r) * K + kt + c], &a_sh[r * BK + scol]);
      }
    }
    __syncthreads();
    #pragma unroll
    for (int ks = 0; ks < BK; ks += 32) {
      bf16x8 af[4], bfr[4];
      #pragma unroll
      for (int i = 0; i < 4; ++i) {
        int ra = wr * 64 + i * 16 + lm;
        if (AF32)
          af[i] = *(const bf16x8*)&a_sh[ra * LDA + ks + quad * 8];
        else
          af[i] = *(const bf16x8*)&a_sh[ra * BK + ((ks + quad * 8) ^ ((ra & 7) << 3))];
      }
      #pragma unroll
      for (int j = 0; j < 4; ++j) {
        int rb = wc * 64 + j * 16 + lm;
        bfr[j] = *(const bf16x8*)&b_sh[rb * BK + ((ks + quad * 8) ^ ((rb & 7) << 3))];
      }
      #pragma unroll
      for (int i = 0; i < 4; ++i)
        #pragma unroll
        for (int j = 0; j < 4; ++j)
          acc[i][j] = __builtin_amdgcn_mfma_f32_16x16x32_bf16(af[i], bfr[j], acc[i][j], 0, 0, 0);
    }
    __syncthreads();
  }

  #pragma unroll
  for (int j = 0; j < 4; ++j) {
    int col = n0 + wc * 64 + j * 16 + lm;
    float bv = bias[col];
    if (MODE == 0) {
      int which = col >> 10;
      int rem = col & 1023;
      int h = rem >> 6, d = rem & 63;
      float mul = (which == 0) ? qscale : 1.0f;
      #pragma unroll
      for (int i = 0; i < 4; ++i)
        #pragma unroll
        for (int r = 0; r < 4; ++r) {
          int row = m0 + wr * 64 + i * 16 + quad * 4 + r;
          int b = row >> 12, l = row & (L_ - 1);
          float v = (acc[i][j][r] + bv) * mul;
          ((__bf16*)out_bf)[(size_t)which * TEN + (((size_t)(b * H_ + h) * L_ + l) * D_ + d)] = (__bf16)v;
        }
    } else {
      #pragma unroll
      for (int i = 0; i < 4; ++i)
        #pragma unroll
        for (int r = 0; r < 4; ++r) {
          int row = m0 + wr * 64 + i * 16 + quad * 4 + r;
          out_f[(size_t)row * N + col] = acc[i][j][r] + bv;
        }
    }
  }
}

// ---------------- neighborhood attention, online softmax (defer-max, exp2) -------
// q pre-scaled by D^-0.5 * log2(e) in the qkv epilogue; rpb staged * log2(e);
// exponentials base-2 (v_exp_f32 native). T13 defer-max: rescale only when
// s - m > 8 (log2 domain). p <= 2^8 bounded, f32 accum safe, normalization exact.
constexpr int KKMAX = 63;
constexpr int TL = 128;
constexpr int LDK = 72;

__global__ __launch_bounds__(256) void natt_kernel(
    const unsigned short* __restrict__ qkv,  // q,k,v each TEN elems, (B,H,L,D) bf16
    const float* __restrict__ rpb,           // H x (2kk-1) f32
    const int* __restrict__ knp,
    unsigned short* __restrict__ attn_out) {  // (B*L) x C bf16
  __shared__ unsigned short k_sh[(TL + KKMAX) * LDK];
  __shared__ unsigned short v_sh[(TL + KKMAX) * LDK];
  __shared__ float rpb_sh[2 * KKMAX + 1];

  const int bh = blockIdx.x;
  const int h = bh & (H_ - 1);
  const int b = bh >> 4;
  const int l0 = blockIdx.y * TL;
  const int t = threadIdx.x;

  int kn = knp[0];
  if (kn > 65536 || kn < 0) {  // guard: value stored as float bits
    union { int i; float f; } u; u.i = kn; kn = (int)u.f;
  }
  int rr = 1;
  while ((rr + 1) * (rr + 1) <= kn) ++rr;
  int kk = rr + 1;
  if (kk > KKMAX) kk = KKMAX;

  int base = l0 - kk / 2;
  if (base < 0) base = 0;
  if (base > L_ - kk) base = L_ - kk;
  int nrows = TL + kk;
  if (nrows > L_ - base) nrows = L_ - base;

  const unsigned short* kg = qkv + TEN + (size_t)bh * L_ * D_;
  const unsigned short* vg = qkv + 2 * TEN + (size_t)bh * L_ * D_;

  for (int i = t; i < nrows * 8; i += 256) {
    int row = i >> 3, c8 = (i & 7) << 3;
    uint4 kv = *(const uint4*)&kg[(size_t)(base + row) * D_ + c8];
    *(uint4*)&k_sh[row * LDK + c8] = kv;
    uint4 vv = *(const uint4*)&vg[(size_t)(base + row) * D_ + c8];
    *(uint4*)&v_sh[row * LDK + c8] = vv;
  }
  int nb = 2 * kk - 1;
  for (int i = t; i < nb; i += 256) rpb_sh[i] = rpb[h * nb + i] * LOG2E;
  __syncthreads();

  const int qi = t >> 1, half = t & 1;
  const int l = l0 + qi;

  const unsigned short* qg = qkv + (size_t)bh * L_ * D_ + (size_t)l * D_ + half * 32;
  float qv[32];
  #pragma unroll
  for (int c = 0; c < 4; ++c) {
    union { uint4 u; unsigned short s[8]; } ld;
    ld.u = *(const uint4*)&qg[c * 8];
    #pragma unroll
    for (int j = 0; j < 8; ++j) qv[c * 8 + j] = bf2f(ld.s[j]);
  }

  int start = l - kk / 2;
  if (start < 0) start = 0;
  if (start > L_ - kk) start = L_ - kk;
  const int srow = start - base;
  const int boff = start - l + kk - 1;

  float m = -1e30f, lsum = 0.0f;
  float accv[32];
  #pragma unroll
  for (int d = 0; d < 32; ++d) accv[d] = 0.0f;

  for (int j = 0; j < kk; ++j) {
    const unsigned short* kr = &k_sh[(srow + j) * LDK + half * 32];
    float partial = 0.0f;
    #pragma unroll
    for (int c = 0; c < 4; ++c) {
      union { uint4 u; unsigned short s[8]; } ld;
      ld.u = *(const uint4*)&kr[c * 8];
      #pragma unroll
      for (int jj = 0; jj < 8; ++jj) partial += qv[c * 8 + jj] * bf2f(ld.s[jj]);
    }
    float s = partial + __shfl_xor(partial, 1) + rpb_sh[boff + j];
    float p;
    if (s - m > 8.0f) {          // defer-max: rescale only on big jumps
      float corr = exp2fast(m - s);
      lsum *= corr;
      #pragma unroll
      for (int d = 0; d < 32; ++d) accv[d] *= corr;
      m = s;
      p = 1.0f;
    } else {
      p = exp2fast(s - m);       // bounded by 2^8
    }
    lsum += p;
    const unsigned short* vr = &v_sh[(srow + j) * LDK + half * 32];
    #pragma unroll
    for (int c = 0; c < 4; ++c) {
      union { uint4 u; unsigned short s[8]; } ld;
      ld.u = *(const uint4*)&vr[c * 8];
      #pragma unroll
      for (int jj = 0; jj < 8; ++jj) accv[c * 8 + jj] += p * bf2f(ld.s[jj]);
    }
  }
  float inv = 1.0f / lsum;
  unsigned short* og = attn_out + ((size_t)(b * L_ + l) * C_ + h * D_ + half * 32);
  #pragma unroll
  for (int c = 0; c < 4; ++c) {
    union { uint4 u; __bf16 h8[8]; } st;
    #pragma unroll
    for (int jj = 0; jj < 8; ++jj) st.h8[jj] = (__bf16)(accv[c * 8 + jj] * inv);
    *(uint4*)&og[c * 8] = st.u;
  }
}

extern "C" void kernel_launch(void* const* d_in, const int* in_sizes, int n_in,
                              void* d_out, int out_size, void* d_ws, size_t ws_size,
                              hipStream_t stream) {
  const float* x      = (const float*)d_in[0];
  const float* w_qkv  = (const float*)d_in[1];
  const float* b_qkv  = (const float*)d_in[2];
  const float* rpb    = (const float*)d_in[3];
  const float* w_proj = (const float*)d_in[4];
  const float* b_proj = (const float*)d_in[5];
  const int* kn       = (const int*)d_in[6];
  float* out          = (float*)d_out;

  unsigned short* ws      = (unsigned short*)d_ws;
  unsigned short* wT_qkv  = ws;                              // 3072x1024 bf16
  unsigned short* wT_proj = wT_qkv + (size_t)3072 * 1024;    // 1024x1024 bf16
  unsigned short* qkv_ws  = wT_proj + (size_t)1024 * 1024;   // 3*TEN bf16
  unsigned short* attn_ws = qkv_ws + 3 * TEN;                // 8192x1024 bf16

  transpose_f32_bf16<<<dim3(3072 / 64, 1024 / 64), 256, 0, stream>>>(w_qkv, wT_qkv, 1024, 3072);
  transpose_f32_bf16<<<dim3(1024 / 64, 1024 / 64), 256, 0, stream>>>(w_proj, wT_proj, 1024, 1024);
  // fused qkv GEMM, A = x (f32, converted in-kernel); q-cols scaled by 0.125*log2e
  gemm_bt_kernel<0, true><<<dim3(3072 / 128, 8192 / 128), 256, 0, stream>>>(
      x, wT_qkv, b_qkv, qkv_ws, nullptr, 8192, 3072, 1024, 0.125f * LOG2E);
  natt_kernel<<<dim3(B_ * H_, L_ / TL), 256, 0, stream>>>(qkv_ws, rpb, kn, attn_ws);
  gemm_bt_kernel<1, false><<<dim3(1024 / 128, 8192 / 128), 256, 0, stream>>>(
      attn_ws, wT_proj, b_proj, nullptr, out, 8192, 1024, 1024, 1.0f);
}

// Round 9
// 220.084 us; speedup vs baseline: 1.1096x; 1.1096x over previous
//
#include <hip/hip_runtime.h>
#include <hip/hip_bf16.h>
#include <stdint.h>

typedef __bf16 bf16x8 __attribute__((ext_vector_type(8)));
typedef float floatx4 __attribute__((ext_vector_type(4)));

#define B_ 2
#define L_ 4096
#define C_ 1024
#define H_ 16
#define D_ 64
constexpr size_t TEN = (size_t)B_ * H_ * L_ * D_;  // 8388608 elems per q/k/v tensor
#define LOG2E 1.4426950408889634f

__device__ __forceinline__ float bf2f(unsigned short u) {
  union { unsigned int i; float f; } x; x.i = ((unsigned int)u) << 16; return x.f;
}
// base-2 exp, maps to v_exp_f32 (AMDGCN's exp IS base-2)
__device__ __forceinline__ float exp2fast(float x) {
  return __builtin_amdgcn_exp2f(x);
}

// direct global->LDS async copy, 16B per lane (global_load_lds_dwordx4)
__device__ __forceinline__ void async_copy16(const unsigned short* g, unsigned short* l) {
  __builtin_amdgcn_global_load_lds(
      (const __attribute__((address_space(1))) unsigned int*)g,
      (__attribute__((address_space(3))) unsigned int*)l,
      16, 0, 0);
}

// ---------------- elementwise f32 -> bf16 (native casts -> v_cvt_pk_bf16_f32) ----
__global__ __launch_bounds__(256) void cvt_f32_bf16_kernel(
    const float* __restrict__ in, unsigned short* __restrict__ out, int n) {
  int i = (blockIdx.x * 256 + threadIdx.x) * 8;
  if (i >= n) return;
  float4 a = *(const float4*)&in[i];
  float4 b = *(const float4*)&in[i + 4];
  union { uint4 u; __bf16 h[8]; } st;
  st.h[0] = (__bf16)a.x; st.h[1] = (__bf16)a.y; st.h[2] = (__bf16)a.z; st.h[3] = (__bf16)a.w;
  st.h[4] = (__bf16)b.x; st.h[5] = (__bf16)b.y; st.h[6] = (__bf16)b.z; st.h[7] = (__bf16)b.w;
  *(uint4*)&out[i] = st.u;
}

// ---------------- transpose f32 in -> bf16 out, dims divisible by 64 ----------------
__global__ __launch_bounds__(256) void transpose_f32_bf16(
    const float* __restrict__ in, unsigned short* __restrict__ out,
    int R, int Ccols) {
  __shared__ float tile[64][65];
  const int bx = blockIdx.x * 64;  // col base in input
  const int by = blockIdx.y * 64;  // row base in input
  const int t = threadIdx.x;
  for (int i = t; i < 1024; i += 256) {
    int r = i >> 4, c4 = (i & 15) << 2;
    float4 v = *(const float4*)&in[(size_t)(by + r) * Ccols + bx + c4];
    tile[r][c4] = v.x; tile[r][c4 + 1] = v.y; tile[r][c4 + 2] = v.z; tile[r][c4 + 3] = v.w;
  }
  __syncthreads();
  for (int i = t; i < 512; i += 256) {
    int r = i >> 3, c8 = (i & 7) << 3;  // r = output row (input col)
    union { uint4 u; __bf16 h[8]; } st;
    #pragma unroll
    for (int j = 0; j < 8; ++j) st.h[j] = (__bf16)tile[c8 + j][r];
    *(uint4*)&out[(size_t)(bx + r) * R + by + c8] = st.u;
  }
}

// ---------------- GEMM: A (MxK, bf16) * Bt^T (Bt is NxK, bf16), MFMA ----------------
// R5 core EXACT (best measured, 76.4 us qkv): 128x128 tile, BK=64, 4 waves,
// global_load_lds width=16 both operands, rule-#21 both-sides XOR swizzle
// (0 bank conflicts measured), 32 KiB LDS, bijective XCD swizzle.
// MODE 0: scatter into q/k/v (B,H,L,D) bf16 with bias; q-cols (<1024) * qscale
// MODE 1: plain C = A*B + bias -> out_f (MxN f32)
template <int MODE>
__global__ __launch_bounds__(256) void gemm_bt_kernel(
    const unsigned short* __restrict__ A, const unsigned short* __restrict__ Bt,
    const float* __restrict__ bias, unsigned short* __restrict__ out_bf,
    float* __restrict__ out_f, int M, int N, int K, float qscale) {
  constexpr int BK = 64;
  __shared__ unsigned short a_sh[128 * BK];
  __shared__ unsigned short b_sh[128 * BK];

  const int t = threadIdx.x;
  // bijective XCD swizzle of flat block id (nwg % 8 == 0: 1536 / 512)
  const int nwgx = gridDim.x;
  const int nwg = nwgx * gridDim.y;
  const int flat = blockIdx.y * nwgx + blockIdx.x;
  const int cpx = nwg >> 3;
  const int swz = (flat & 7) * cpx + (flat >> 3);
  const int n0 = (swz % nwgx) * 128;
  const int m0 = (swz / nwgx) * 128;

  const int wave = t >> 6, lane = t & 63;
  const int wr = wave >> 1, wc = wave & 1;
  const int lm = lane & 15, quad = lane >> 4;

  const int soff = t * 8;           // base element offset for p=0
  const int srow = soff >> 6;       // 0..31
  const int scol = soff & 63;       // multiple of 8 elems = 16B aligned

  floatx4 acc[4][4];
  #pragma unroll
  for (int i = 0; i < 4; ++i)
    #pragma unroll
    for (int j = 0; j < 4; ++j) acc[i][j] = (floatx4)0.0f;

  for (int kt = 0; kt < K; kt += BK) {
    #pragma unroll
    for (int p = 0; p < 4; ++p) {
      int r = srow + p * 32;
      int c = scol ^ ((r & 7) << 3);   // inverse swizzle on source col
      int off = r * BK + scol;          // linear dest
      async_copy16(&A[(size_t)(m0 + r) * K + kt + c], &a_sh[off]);
      async_copy16(&Bt[(size_t)(n0 + r) * K + kt + c], &b_sh[off]);
    }
    __syncthreads();
    #pragma unroll
    for (int ks = 0; ks < BK; ks += 32) {
      bf16x8 af[4], bfr[4];
      #pragma unroll
      for (int i = 0; i < 4; ++i) {
        int ra = wr * 64 + i * 16 + lm;
        af[i] = *(const bf16x8*)&a_sh[ra * BK + ((ks + quad * 8) ^ ((ra & 7) << 3))];
      }
      #pragma unroll
      for (int j = 0; j < 4; ++j) {
        int rb = wc * 64 + j * 16 + lm;
        bfr[j] = *(const bf16x8*)&b_sh[rb * BK + ((ks + quad * 8) ^ ((rb & 7) << 3))];
      }
      #pragma unroll
      for (int i = 0; i < 4; ++i)
        #pragma unroll
        for (int j = 0; j < 4; ++j)
          acc[i][j] = __builtin_amdgcn_mfma_f32_16x16x32_bf16(af[i], bfr[j], acc[i][j], 0, 0, 0);
    }
    __syncthreads();
  }

  #pragma unroll
  for (int j = 0; j < 4; ++j) {
    int col = n0 + wc * 64 + j * 16 + lm;
    float bv = bias[col];
    if (MODE == 0) {
      int which = col >> 10;
      int rem = col & 1023;
      int h = rem >> 6, d = rem & 63;
      float mul = (which == 0) ? qscale : 1.0f;
      #pragma unroll
      for (int i = 0; i < 4; ++i)
        #pragma unroll
        for (int r = 0; r < 4; ++r) {
          int row = m0 + wr * 64 + i * 16 + quad * 4 + r;
          int b = row >> 12, l = row & (L_ - 1);
          float v = (acc[i][j][r] + bv) * mul;
          ((__bf16*)out_bf)[(size_t)which * TEN + (((size_t)(b * H_ + h) * L_ + l) * D_ + d)] = (__bf16)v;
        }
    } else {
      #pragma unroll
      for (int i = 0; i < 4; ++i)
        #pragma unroll
        for (int r = 0; r < 4; ++r) {
          int row = m0 + wr * 64 + i * 16 + quad * 4 + r;
          out_f[(size_t)row * N + col] = acc[i][j][r] + bv;
        }
    }
  }
}

// ---------------- neighborhood attention, online softmax (defer-max, exp2) -------
// q pre-scaled by D^-0.5 * log2(e) in the qkv epilogue; rpb staged * log2(e);
// exponentials base-2 (v_exp_f32 native). T13 defer-max: rescale only when
// s - m > 8 (log2 domain). p <= 2^8 bounded, f32 accum safe, normalization exact.
constexpr int KKMAX = 63;
constexpr int TL = 128;
constexpr int LDK = 72;

__global__ __launch_bounds__(256) void natt_kernel(
    const unsigned short* __restrict__ qkv,  // q,k,v each TEN elems, (B,H,L,D) bf16
    const float* __restrict__ rpb,           // H x (2kk-1) f32
    const int* __restrict__ knp,
    unsigned short* __restrict__ attn_out) {  // (B*L) x C bf16
  __shared__ unsigned short k_sh[(TL + KKMAX) * LDK];
  __shared__ unsigned short v_sh[(TL + KKMAX) * LDK];
  __shared__ float rpb_sh[2 * KKMAX + 1];

  const int bh = blockIdx.x;
  const int h = bh & (H_ - 1);
  const int b = bh >> 4;
  const int l0 = blockIdx.y * TL;
  const int t = threadIdx.x;

  int kn = knp[0];
  if (kn > 65536 || kn < 0) {  // guard: value stored as float bits
    union { int i; float f; } u; u.i = kn; kn = (int)u.f;
  }
  int rr = 1;
  while ((rr + 1) * (rr + 1) <= kn) ++rr;
  int kk = rr + 1;
  if (kk > KKMAX) kk = KKMAX;

  int base = l0 - kk / 2;
  if (base < 0) base = 0;
  if (base > L_ - kk) base = L_ - kk;
  int nrows = TL + kk;
  if (nrows > L_ - base) nrows = L_ - base;

  const unsigned short* kg = qkv + TEN + (size_t)bh * L_ * D_;
  const unsigned short* vg = qkv + 2 * TEN + (size_t)bh * L_ * D_;

  for (int i = t; i < nrows * 8; i += 256) {
    int row = i >> 3, c8 = (i & 7) << 3;
    uint4 kv = *(const uint4*)&kg[(size_t)(base + row) * D_ + c8];
    *(uint4*)&k_sh[row * LDK + c8] = kv;
    uint4 vv = *(const uint4*)&vg[(size_t)(base + row) * D_ + c8];
    *(uint4*)&v_sh[row * LDK + c8] = vv;
  }
  int nb = 2 * kk - 1;
  for (int i = t; i < nb; i += 256) rpb_sh[i] = rpb[h * nb + i] * LOG2E;
  __syncthreads();

  const int qi = t >> 1, half = t & 1;
  const int l = l0 + qi;

  const unsigned short* qg = qkv + (size_t)bh * L_ * D_ + (size_t)l * D_ + half * 32;
  float qv[32];
  #pragma unroll
  for (int c = 0; c < 4; ++c) {
    union { uint4 u; unsigned short s[8]; } ld;
    ld.u = *(const uint4*)&qg[c * 8];
    #pragma unroll
    for (int j = 0; j < 8; ++j) qv[c * 8 + j] = bf2f(ld.s[j]);
  }

  int start = l - kk / 2;
  if (start < 0) start = 0;
  if (start > L_ - kk) start = L_ - kk;
  const int srow = start - base;
  const int boff = start - l + kk - 1;

  float m = -1e30f, lsum = 0.0f;
  float accv[32];
  #pragma unroll
  for (int d = 0; d < 32; ++d) accv[d] = 0.0f;

  for (int j = 0; j < kk; ++j) {
    const unsigned short* kr = &k_sh[(srow + j) * LDK + half * 32];
    float partial = 0.0f;
    #pragma unroll
    for (int c = 0; c < 4; ++c) {
      union { uint4 u; unsigned short s[8]; } ld;
      ld.u = *(const uint4*)&kr[c * 8];
      #pragma unroll
      for (int jj = 0; jj < 8; ++jj) partial += qv[c * 8 + jj] * bf2f(ld.s[jj]);
    }
    float s = partial + __shfl_xor(partial, 1) + rpb_sh[boff + j];
    float p;
    if (s - m > 8.0f) {          // defer-max: rescale only on big jumps
      float corr = exp2fast(m - s);
      lsum *= corr;
      #pragma unroll
      for (int d = 0; d < 32; ++d) accv[d] *= corr;
      m = s;
      p = 1.0f;
    } else {
      p = exp2fast(s - m);       // bounded by 2^8
    }
    lsum += p;
    const unsigned short* vr = &v_sh[(srow + j) * LDK + half * 32];
    #pragma unroll
    for (int c = 0; c < 4; ++c) {
      union { uint4 u; unsigned short s[8]; } ld;
      ld.u = *(const uint4*)&vr[c * 8];
      #pragma unroll
      for (int jj = 0; jj < 8; ++jj) accv[c * 8 + jj] += p * bf2f(ld.s[jj]);
    }
  }
  float inv = 1.0f / lsum;
  unsigned short* og = attn_out + ((size_t)(b * L_ + l) * C_ + h * D_ + half * 32);
  #pragma unroll
  for (int c = 0; c < 4; ++c) {
    union { uint4 u; __bf16 h8[8]; } st;
    #pragma unroll
    for (int jj = 0; jj < 8; ++jj) st.h8[jj] = (__bf16)(accv[c * 8 + jj] * inv);
    *(uint4*)&og[c * 8] = st.u;
  }
}

extern "C" void kernel_launch(void* const* d_in, const int* in_sizes, int n_in,
                              void* d_out, int out_size, void* d_ws, size_t ws_size,
                              hipStream_t stream) {
  const float* x      = (const float*)d_in[0];
  const float* w_qkv  = (const float*)d_in[1];
  const float* b_qkv  = (const float*)d_in[2];
  const float* rpb    = (const float*)d_in[3];
  const float* w_proj = (const float*)d_in[4];
  const float* b_proj = (const float*)d_in[5];
  const int* kn       = (const int*)d_in[6];
  float* out          = (float*)d_out;

  unsigned short* ws      = (unsigned short*)d_ws;
  unsigned short* wT_qkv  = ws;                              // 3072x1024 bf16
  unsigned short* wT_proj = wT_qkv + (size_t)3072 * 1024;    // 1024x1024 bf16
  unsigned short* x_bf    = wT_proj + (size_t)1024 * 1024;   // 8192x1024 bf16
  unsigned short* qkv_ws  = x_bf + (size_t)8192 * 1024;      // 3*TEN bf16
  unsigned short* attn_ws = qkv_ws + 3 * TEN;                // 8192x1024 bf16

  cvt_f32_bf16_kernel<<<(8192 * 1024) / (256 * 8), 256, 0, stream>>>(x, x_bf, 8192 * 1024);
  transpose_f32_bf16<<<dim3(3072 / 64, 1024 / 64), 256, 0, stream>>>(w_qkv, wT_qkv, 1024, 3072);
  transpose_f32_bf16<<<dim3(1024 / 64, 1024 / 64), 256, 0, stream>>>(w_proj, wT_proj, 1024, 1024);
  // fused qkv GEMM (R5 exact); q-cols scaled by D^-0.5 * log2(e) for exp2-domain natt
  gemm_bt_kernel<0><<<dim3(3072 / 128, 8192 / 128), 256, 0, stream>>>(
      x_bf, wT_qkv, b_qkv, qkv_ws, nullptr, 8192, 3072, 1024, 0.125f * LOG2E);
  natt_kernel<<<dim3(B_ * H_, L_ / TL), 256, 0, stream>>>(qkv_ws, rpb, kn, attn_ws);
  gemm_bt_kernel<1><<<dim3(1024 / 128, 8192 / 128), 256, 0, stream>>>(
      attn_ws, wT_proj, b_proj, nullptr, out, 8192, 1024, 1024, 1.0f);
}

// Round 10
// 213.430 us; speedup vs baseline: 1.1442x; 1.0312x over previous
//
#include <hip/hip_runtime.h>
#include <hip/hip_bf16.h>
#include <stdint.h>

typedef __bf16 bf16x8 __attribute__((ext_vector_type(8)));
typedef float floatx4 __attribute__((ext_vector_type(4)));

#define B_ 2
#define L_ 4096
#define C_ 1024
#define H_ 16
#define D_ 64
constexpr size_t TEN = (size_t)B_ * H_ * L_ * D_;  // 8388608 elems per q/k/v tensor
#define LOG2E 1.4426950408889634f

__device__ __forceinline__ float bf2f(unsigned short u) {
  union { unsigned int i; float f; } x; x.i = ((unsigned int)u) << 16; return x.f;
}
// base-2 exp, maps to v_exp_f32 (AMDGCN's exp IS base-2)
__device__ __forceinline__ float exp2fast(float x) {
  return __builtin_amdgcn_exp2f(x);
}

// direct global->LDS async copy, 16B per lane (global_load_lds_dwordx4)
__device__ __forceinline__ void async_copy16(const unsigned short* g, unsigned short* l) {
  __builtin_amdgcn_global_load_lds(
      (const __attribute__((address_space(1))) unsigned int*)g,
      (__attribute__((address_space(3))) unsigned int*)l,
      16, 0, 0);
}

// ---------------- fused prep: x cvt (blocks 0..4095), w_qkv^T (next 768),
// ---------------- w_proj^T (next 256). Branches are block-uniform.
__global__ __launch_bounds__(256) void prep_kernel(
    const float* __restrict__ x, unsigned short* __restrict__ x_bf,
    const float* __restrict__ w_qkv, unsigned short* __restrict__ wT_qkv,
    const float* __restrict__ w_proj, unsigned short* __restrict__ wT_proj) {
  __shared__ float tile[64][65];
  const int bid = blockIdx.x;
  const int t = threadIdx.x;

  if (bid < 4096) {  // f32 -> bf16 elementwise (native casts -> v_cvt_pk_bf16_f32)
    int i = (bid * 256 + t) * 8;
    float4 a = *(const float4*)&x[i];
    float4 b = *(const float4*)&x[i + 4];
    union { uint4 u; __bf16 h[8]; } st;
    st.h[0] = (__bf16)a.x; st.h[1] = (__bf16)a.y; st.h[2] = (__bf16)a.z; st.h[3] = (__bf16)a.w;
    st.h[4] = (__bf16)b.x; st.h[5] = (__bf16)b.y; st.h[6] = (__bf16)b.z; st.h[7] = (__bf16)b.w;
    *(uint4*)&x_bf[i] = st.u;
    return;
  }

  // transpose f32 in (R x Ccols) -> bf16 out (Ccols x R)
  const float* in; unsigned short* out; int Ccols, bx, by;
  if (bid < 4096 + 768) {
    int r = bid - 4096;
    in = w_qkv; out = wT_qkv; Ccols = 3072;
    bx = (r % 48) * 64; by = (r / 48) * 64;
  } else {
    int r = bid - 4096 - 768;
    in = w_proj; out = wT_proj; Ccols = 1024;
    bx = (r % 16) * 64; by = (r / 16) * 64;
  }
  constexpr int R = 1024;
  for (int i = t; i < 1024; i += 256) {
    int r = i >> 4, c4 = (i & 15) << 2;
    float4 v = *(const float4*)&in[(size_t)(by + r) * Ccols + bx + c4];
    tile[r][c4] = v.x; tile[r][c4 + 1] = v.y; tile[r][c4 + 2] = v.z; tile[r][c4 + 3] = v.w;
  }
  __syncthreads();
  for (int i = t; i < 512; i += 256) {
    int r = i >> 3, c8 = (i & 7) << 3;  // r = output row (input col)
    union { uint4 u; __bf16 h[8]; } st;
    #pragma unroll
    for (int j = 0; j < 8; ++j) st.h[j] = (__bf16)tile[c8 + j][r];
    *(uint4*)&out[(size_t)(bx + r) * R + by + c8] = st.u;
  }
}

// ---------------- GEMM: A (MxK, bf16) * Bt^T (Bt is NxK, bf16), MFMA ----------------
// R5 core EXACT (best measured): 128x128 tile, BK=64, 4 waves, global_load_lds
// width=16 both operands, rule-#21 both-sides XOR swizzle (0 bank conflicts),
// 32 KiB LDS, bijective XCD swizzle.
// MODE 0: scatter into q/k/v (B,H,L,D) bf16 with bias; q-cols (<1024) * qscale
// MODE 1: plain C = A*B + bias -> out_f (MxN f32)
template <int MODE>
__global__ __launch_bounds__(256) void gemm_bt_kernel(
    const unsigned short* __restrict__ A, const unsigned short* __restrict__ Bt,
    const float* __restrict__ bias, unsigned short* __restrict__ out_bf,
    float* __restrict__ out_f, int M, int N, int K, float qscale) {
  constexpr int BK = 64;
  __shared__ unsigned short a_sh[128 * BK];
  __shared__ unsigned short b_sh[128 * BK];

  const int t = threadIdx.x;
  // bijective XCD swizzle of flat block id (nwg % 8 == 0: 1536 / 512)
  const int nwgx = gridDim.x;
  const int nwg = nwgx * gridDim.y;
  const int flat = blockIdx.y * nwgx + blockIdx.x;
  const int cpx = nwg >> 3;
  const int swz = (flat & 7) * cpx + (flat >> 3);
  const int n0 = (swz % nwgx) * 128;
  const int m0 = (swz / nwgx) * 128;

  const int wave = t >> 6, lane = t & 63;
  const int wr = wave >> 1, wc = wave & 1;
  const int lm = lane & 15, quad = lane >> 4;

  const int soff = t * 8;           // base element offset for p=0
  const int srow = soff >> 6;       // 0..31
  const int scol = soff & 63;       // multiple of 8 elems = 16B aligned

  floatx4 acc[4][4];
  #pragma unroll
  for (int i = 0; i < 4; ++i)
    #pragma unroll
    for (int j = 0; j < 4; ++j) acc[i][j] = (floatx4)0.0f;

  for (int kt = 0; kt < K; kt += BK) {
    #pragma unroll
    for (int p = 0; p < 4; ++p) {
      int r = srow + p * 32;
      int c = scol ^ ((r & 7) << 3);   // inverse swizzle on source col
      int off = r * BK + scol;          // linear dest
      async_copy16(&A[(size_t)(m0 + r) * K + kt + c], &a_sh[off]);
      async_copy16(&Bt[(size_t)(n0 + r) * K + kt + c], &b_sh[off]);
    }
    __syncthreads();
    #pragma unroll
    for (int ks = 0; ks < BK; ks += 32) {
      bf16x8 af[4], bfr[4];
      #pragma unroll
      for (int i = 0; i < 4; ++i) {
        int ra = wr * 64 + i * 16 + lm;
        af[i] = *(const bf16x8*)&a_sh[ra * BK + ((ks + quad * 8) ^ ((ra & 7) << 3))];
      }
      #pragma unroll
      for (int j = 0; j < 4; ++j) {
        int rb = wc * 64 + j * 16 + lm;
        bfr[j] = *(const bf16x8*)&b_sh[rb * BK + ((ks + quad * 8) ^ ((rb & 7) << 3))];
      }
      #pragma unroll
      for (int i = 0; i < 4; ++i)
        #pragma unroll
        for (int j = 0; j < 4; ++j)
          acc[i][j] = __builtin_amdgcn_mfma_f32_16x16x32_bf16(af[i], bfr[j], acc[i][j], 0, 0, 0);
    }
    __syncthreads();
  }

  #pragma unroll
  for (int j = 0; j < 4; ++j) {
    int col = n0 + wc * 64 + j * 16 + lm;
    float bv = bias[col];
    if (MODE == 0) {
      int which = col >> 10;
      int rem = col & 1023;
      int h = rem >> 6, d = rem & 63;
      float mul = (which == 0) ? qscale : 1.0f;
      #pragma unroll
      for (int i = 0; i < 4; ++i)
        #pragma unroll
        for (int r = 0; r < 4; ++r) {
          int row = m0 + wr * 64 + i * 16 + quad * 4 + r;
          int b = row >> 12, l = row & (L_ - 1);
          float v = (acc[i][j][r] + bv) * mul;
          ((__bf16*)out_bf)[(size_t)which * TEN + (((size_t)(b * H_ + h) * L_ + l) * D_ + d)] = (__bf16)v;
        }
    } else {
      #pragma unroll
      for (int i = 0; i < 4; ++i)
        #pragma unroll
        for (int r = 0; r < 4; ++r) {
          int row = m0 + wr * 64 + i * 16 + quad * 4 + r;
          out_f[(size_t)row * N + col] = acc[i][j][r] + bv;
        }
    }
  }
}

// ---------------- neighborhood attention, online softmax (defer-max, exp2) -------
// q pre-scaled by D^-0.5 * log2(e) in the qkv epilogue; rpb staged * log2(e);
// exponentials base-2 (v_exp_f32 native). T13 defer-max: rescale only when
// s - m > 8 (log2 domain). p <= 2^8 bounded, f32 accum safe, normalization exact.
constexpr int KKMAX = 63;
constexpr int TL = 128;
constexpr int LDK = 72;

__global__ __launch_bounds__(256) void natt_kernel(
    const unsigned short* __restrict__ qkv,  // q,k,v each TEN elems, (B,H,L,D) bf16
    const float* __restrict__ rpb,           // H x (2kk-1) f32
    const int* __restrict__ knp,
    unsigned short* __restrict__ attn_out) {  // (B*L) x C bf16
  __shared__ unsigned short k_sh[(TL + KKMAX) * LDK];
  __shared__ unsigned short v_sh[(TL + KKMAX) * LDK];
  __shared__ float rpb_sh[2 * KKMAX + 1];

  const int bh = blockIdx.x;
  const int h = bh & (H_ - 1);
  const int b = bh >> 4;
  const int l0 = blockIdx.y * TL;
  const int t = threadIdx.x;

  int kn = knp[0];
  if (kn > 65536 || kn < 0) {  // guard: value stored as float bits
    union { int i; float f; } u; u.i = kn; kn = (int)u.f;
  }
  int rr = 1;
  while ((rr + 1) * (rr + 1) <= kn) ++rr;
  int kk = rr + 1;
  if (kk > KKMAX) kk = KKMAX;

  int base = l0 - kk / 2;
  if (base < 0) base = 0;
  if (base > L_ - kk) base = L_ - kk;
  int nrows = TL + kk;
  if (nrows > L_ - base) nrows = L_ - base;

  const unsigned short* kg = qkv + TEN + (size_t)bh * L_ * D_;
  const unsigned short* vg = qkv + 2 * TEN + (size_t)bh * L_ * D_;

  for (int i = t; i < nrows * 8; i += 256) {
    int row = i >> 3, c8 = (i & 7) << 3;
    uint4 kv = *(const uint4*)&kg[(size_t)(base + row) * D_ + c8];
    *(uint4*)&k_sh[row * LDK + c8] = kv;
    uint4 vv = *(const uint4*)&vg[(size_t)(base + row) * D_ + c8];
    *(uint4*)&v_sh[row * LDK + c8] = vv;
  }
  int nb = 2 * kk - 1;
  for (int i = t; i < nb; i += 256) rpb_sh[i] = rpb[h * nb + i] * LOG2E;
  __syncthreads();

  const int qi = t >> 1, half = t & 1;
  const int l = l0 + qi;

  const unsigned short* qg = qkv + (size_t)bh * L_ * D_ + (size_t)l * D_ + half * 32;
  float qv[32];
  #pragma unroll
  for (int c = 0; c < 4; ++c) {
    union { uint4 u; unsigned short s[8]; } ld;
    ld.u = *(const uint4*)&qg[c * 8];
    #pragma unroll
    for (int j = 0; j < 8; ++j) qv[c * 8 + j] = bf2f(ld.s[j]);
  }

  int start = l - kk / 2;
  if (start < 0) start = 0;
  if (start > L_ - kk) start = L_ - kk;
  const int srow = start - base;
  const int boff = start - l + kk - 1;

  float m = -1e30f, lsum = 0.0f;
  float accv[32];
  #pragma unroll
  for (int d = 0; d < 32; ++d) accv[d] = 0.0f;

  for (int j = 0; j < kk; ++j) {
    const unsigned short* kr = &k_sh[(srow + j) * LDK + half * 32];
    float partial = 0.0f;
    #pragma unroll
    for (int c = 0; c < 4; ++c) {
      union { uint4 u; unsigned short s[8]; } ld;
      ld.u = *(const uint4*)&kr[c * 8];
      #pragma unroll
      for (int jj = 0; jj < 8; ++jj) partial += qv[c * 8 + jj] * bf2f(ld.s[jj]);
    }
    float s = partial + __shfl_xor(partial, 1) + rpb_sh[boff + j];
    float p;
    if (s - m > 8.0f) {          // defer-max: rescale only on big jumps
      float corr = exp2fast(m - s);
      lsum *= corr;
      #pragma unroll
      for (int d = 0; d < 32; ++d) accv[d] *= corr;
      m = s;
      p = 1.0f;
    } else {
      p = exp2fast(s - m);       // bounded by 2^8
    }
    lsum += p;
    const unsigned short* vr = &v_sh[(srow + j) * LDK + half * 32];
    #pragma unroll
    for (int c = 0; c < 4; ++c) {
      union { uint4 u; unsigned short s[8]; } ld;
      ld.u = *(const uint4*)&vr[c * 8];
      #pragma unroll
      for (int jj = 0; jj < 8; ++jj) accv[c * 8 + jj] += p * bf2f(ld.s[jj]);
    }
  }
  float inv = 1.0f / lsum;
  unsigned short* og = attn_out + ((size_t)(b * L_ + l) * C_ + h * D_ + half * 32);
  #pragma unroll
  for (int c = 0; c < 4; ++c) {
    union { uint4 u; __bf16 h8[8]; } st;
    #pragma unroll
    for (int jj = 0; jj < 8; ++jj) st.h8[jj] = (__bf16)(accv[c * 8 + jj] * inv);
    *(uint4*)&og[c * 8] = st.u;
  }
}

extern "C" void kernel_launch(void* const* d_in, const int* in_sizes, int n_in,
                              void* d_out, int out_size, void* d_ws, size_t ws_size,
                              hipStream_t stream) {
  const float* x      = (const float*)d_in[0];
  const float* w_qkv  = (const float*)d_in[1];
  const float* b_qkv  = (const float*)d_in[2];
  const float* rpb    = (const float*)d_in[3];
  const float* w_proj = (const float*)d_in[4];
  const float* b_proj = (const float*)d_in[5];
  const int* kn       = (const int*)d_in[6];
  float* out          = (float*)d_out;

  unsigned short* ws      = (unsigned short*)d_ws;
  unsigned short* wT_qkv  = ws;                              // 3072x1024 bf16
  unsigned short* wT_proj = wT_qkv + (size_t)3072 * 1024;    // 1024x1024 bf16
  unsigned short* x_bf    = wT_proj + (size_t)1024 * 1024;   // 8192x1024 bf16
  unsigned short* qkv_ws  = x_bf + (size_t)8192 * 1024;      // 3*TEN bf16
  unsigned short* attn_ws = qkv_ws + 3 * TEN;                // 8192x1024 bf16

  // fused prep: cvt (4096 blocks) + w_qkv^T (768) + w_proj^T (256)
  prep_kernel<<<4096 + 768 + 256, 256, 0, stream>>>(
      x, x_bf, w_qkv, wT_qkv, w_proj, wT_proj);
  // fused qkv GEMM (R5 exact); q-cols scaled by D^-0.5 * log2(e) for exp2-domain natt
  gemm_bt_kernel<0><<<dim3(3072 / 128, 8192 / 128), 256, 0, stream>>>(
      x_bf, wT_qkv, b_qkv, qkv_ws, nullptr, 8192, 3072, 1024, 0.125f * LOG2E);
  natt_kernel<<<dim3(B_ * H_, L_ / TL), 256, 0, stream>>>(qkv_ws, rpb, kn, attn_ws);
  gemm_bt_kernel<1><<<dim3(1024 / 128, 8192 / 128), 256, 0, stream>>>(
      attn_ws, wT_proj, b_proj, nullptr, out, 8192, 1024, 1024, 1.0f);
}